// Round 5
// baseline (786.511 us; speedup 1.0000x reference)
//
#include <hip/hip_runtime.h>

// Problem constants
#define BSZ 8
#define NH 12
#define LSEQ 1024
#define DMODEL 768
#define DHEAD 64
#define OUT_ELEMS 6291456   // 8*1024*768
#define ATTN_ELEMS 8388608  // 8*1024*1024

typedef __attribute__((ext_vector_type(8))) short short8;   // 8 x bf16 (4 VGPRs)
typedef __attribute__((ext_vector_type(4))) float f32x4;

__device__ __forceinline__ int   f2i(float x) { union { float f; int i; } c; c.f = x; return c.i; }
__device__ __forceinline__ float i2f(int x)   { union { int i; float f; } c; c.i = x; return c.f; }

__device__ __forceinline__ unsigned short f2bf(float x) {
    union { float f; unsigned u; } c; c.f = x;
    unsigned r = (c.u + 0x7FFF + ((c.u >> 16) & 1)) >> 16;   // RNE
    return (unsigned short)r;
}
__device__ __forceinline__ float bf2f(unsigned short h) {
    union { float f; unsigned u; } c; c.u = ((unsigned)h) << 16;
    return c.f;
}
__device__ __forceinline__ void split2(float x, unsigned short& h, unsigned short& l) {
    h = f2bf(x);
    l = f2bf(x - bf2f(h));
}

// ---- DPP wave-64 reductions (4 interleaved chains; result broadcast) ----
template<int CTRL>
__device__ __forceinline__ float dppadd(float v) {
    return v + i2f(__builtin_amdgcn_update_dpp(0, f2i(v), CTRL, 0xF, 0xF, true));
}
template<int CTRL>
__device__ __forceinline__ float dppmax(float v) {
    return fmaxf(v, i2f(__builtin_amdgcn_update_dpp(f2i(v), f2i(v), CTRL, 0xF, 0xF, false)));
}

__device__ __forceinline__ void wsum4(float s[4]) {
#define WS(CTRL) _Pragma("unroll") for (int rr = 0; rr < 4; ++rr) { s[rr] = dppadd<CTRL>(s[rr]); }
    WS(0x111) WS(0x112) WS(0x114) WS(0x118) WS(0x142) WS(0x143)
#undef WS
#pragma unroll
    for (int rr = 0; rr < 4; ++rr) s[rr] = i2f(__builtin_amdgcn_readlane(f2i(s[rr]), 63));
}

__device__ __forceinline__ void wsummax4(float s[4], float m[4]) {
#define WS(CTRL) _Pragma("unroll") for (int rr = 0; rr < 4; ++rr) { s[rr] = dppadd<CTRL>(s[rr]); m[rr] = dppmax<CTRL>(m[rr]); }
    WS(0x111) WS(0x112) WS(0x114) WS(0x118) WS(0x142) WS(0x143)
#undef WS
#pragma unroll
    for (int rr = 0; rr < 4; ++rr) {
        s[rr] = i2f(__builtin_amdgcn_readlane(f2i(s[rr]), 63));
        m[rr] = i2f(__builtin_amdgcn_readlane(f2i(m[rr]), 63));
    }
}

// ---------------------------------------------------------------------------
// proj_mfma: C = A @ W^T + bias via split-bf16 3-pass MFMA.
// R5: Q path scaled by 0.125 (1/sqrt(DHEAD)) — exact power-of-2 fold.
// ---------------------------------------------------------------------------
__global__ __launch_bounds__(256) void proj_mfma(
    const float* __restrict__ qin, const float* __restrict__ kin,
    const float* __restrict__ Wq, const float* __restrict__ bq,
    const float* __restrict__ Wk, const float* __restrict__ bk,
    unsigned short* __restrict__ ws) {
    const float* A; const float* W; const float* bias;
    unsigned short* hi; unsigned short* lo;
    if (blockIdx.z == 0) { A = qin; W = Wq; bias = bq; hi = ws;                lo = ws + OUT_ELEMS; }
    else                 { A = kin; W = Wk; bias = bk; hi = ws + 2*OUT_ELEMS; lo = ws + 3*OUT_ELEMS; }
    const float oscale = (blockIdx.z == 0) ? 0.125f : 1.0f;

    __shared__ unsigned short Ah[128][32], Al[128][32];
    __shared__ unsigned short Bh[128][32], Bl[128][32];

    const int t    = threadIdx.x;
    const int lane = t & 63;
    const int w    = t >> 6;
    const int wr   = w >> 1, wc = w & 1;
    const int mrow = lane & 15, quad = lane >> 4;
    const int m0   = blockIdx.y * 128;
    const int n0   = blockIdx.x * 128;

    const int srow = t >> 3;
    const int scol = (t & 7) * 4;

    f32x4 acc[4][4];
#pragma unroll
    for (int i = 0; i < 4; ++i)
#pragma unroll
        for (int j = 0; j < 4; ++j) acc[i][j] = (f32x4){0.f, 0.f, 0.f, 0.f};

    for (int k0 = 0; k0 < DMODEL; k0 += 32) {
        float4 av[4], wv[4];
#pragma unroll
        for (int i = 0; i < 4; ++i) {
            av[i] = *(const float4*)&A[(size_t)(m0 + srow + i * 32) * DMODEL + k0 + scol];
            wv[i] = *(const float4*)&W[(size_t)(n0 + srow + i * 32) * DMODEL + k0 + scol];
        }
        __syncthreads();
#pragma unroll
        for (int i = 0; i < 4; ++i) {
            ushort4 h4, l4;
            split2(av[i].x, h4.x, l4.x); split2(av[i].y, h4.y, l4.y);
            split2(av[i].z, h4.z, l4.z); split2(av[i].w, h4.w, l4.w);
            *(ushort4*)&Ah[srow + i * 32][scol] = h4;
            *(ushort4*)&Al[srow + i * 32][scol] = l4;
            split2(wv[i].x, h4.x, l4.x); split2(wv[i].y, h4.y, l4.y);
            split2(wv[i].z, h4.z, l4.z); split2(wv[i].w, h4.w, l4.w);
            *(ushort4*)&Bh[srow + i * 32][scol] = h4;
            *(ushort4*)&Bl[srow + i * 32][scol] = l4;
        }
        __syncthreads();

        short8 ah[4], al[4], bh[4], bl[4];
#pragma unroll
        for (int i = 0; i < 4; ++i) {
            ah[i] = *(const short8*)&Ah[wr * 64 + i * 16 + mrow][quad * 8];
            al[i] = *(const short8*)&Al[wr * 64 + i * 16 + mrow][quad * 8];
            bh[i] = *(const short8*)&Bh[wc * 64 + i * 16 + mrow][quad * 8];
            bl[i] = *(const short8*)&Bl[wc * 64 + i * 16 + mrow][quad * 8];
        }
#pragma unroll
        for (int i = 0; i < 4; ++i)
#pragma unroll
            for (int j = 0; j < 4; ++j) {
                acc[i][j] = __builtin_amdgcn_mfma_f32_16x16x32_bf16(al[i], bh[j], acc[i][j], 0, 0, 0);
                acc[i][j] = __builtin_amdgcn_mfma_f32_16x16x32_bf16(ah[i], bl[j], acc[i][j], 0, 0, 0);
                acc[i][j] = __builtin_amdgcn_mfma_f32_16x16x32_bf16(ah[i], bh[j], acc[i][j], 0, 0, 0);
            }
    }

#pragma unroll
    for (int j = 0; j < 4; ++j) {
        const int ng = n0 + wc * 64 + j * 16 + mrow;
        const float bj = bias[ng];
        const int hh = ng >> 6, dd = ng & 63;
#pragma unroll
        for (int i = 0; i < 4; ++i) {
#pragma unroll
            for (int reg = 0; reg < 4; ++reg) {
                const int mg = m0 + wr * 64 + i * 16 + quad * 4 + reg;
                const float c = (acc[i][j][reg] + bj) * oscale;
                unsigned short ch, cl;
                split2(c, ch, cl);
                const size_t idx = (((size_t)(mg >> 10) * NH + hh) * LSEQ + (mg & 1023)) * DHEAD + dd;
                hi[idx] = ch;
                lo[idx] = cl;
            }
        }
    }
}

// ---------------------------------------------------------------------------
// Fused scores + sparsemax + head-mean.
// R5: 8 q-rows per block, 128 threads (2 waves). Wave w: col strip 512w,
// sparsemax rows 4w..4w+3. A-frag rows q0+(mrow&7) (rows 8-15 dup -> quads
// 2,3 skip S writes: 2-way=free bank aliasing). S = 8x1024 f32 = 32 KB.
// Head-mean accumulated DIRECTLY from sparsemax registers (z-layout), no
// p-writeback, no head-mean LDS phase. Tree-structured serial sums.
// ---------------------------------------------------------------------------
__global__ __launch_bounds__(128) void attn_kernel(
    const unsigned short* __restrict__ ws, float* __restrict__ attn_out) {
    __shared__ float S[8 * 1024];     // 32 KB score tile

    const unsigned short* Qhi = ws;
    const unsigned short* Qlo = ws + OUT_ELEMS;
    const unsigned short* Khi = ws + 2 * OUT_ELEMS;
    const unsigned short* Klo = ws + 3 * OUT_ELEMS;

    const int t = threadIdx.x;        // 0..127
    const int lane = t & 63;
    const int w = t >> 6;             // wave 0..1
    const int b = blockIdx.y;
    const int q0 = blockIdx.x * 8;

    const int mrow = lane & 15;
    const int quad = lane >> 4;

    f32x4 acc[4][4];                  // head-mean partials, z-layout: [row rr][col grp c]
#pragma unroll
    for (int rr = 0; rr < 4; ++rr)
#pragma unroll
        for (int c = 0; c < 4; ++c) acc[rr][c] = (f32x4){0.f, 0.f, 0.f, 0.f};

    for (int h = 0; h < NH; ++h) {
        const size_t hb = ((size_t)b * NH + h) * (LSEQ * DHEAD);

        // A frags: rows q0+(mrow&7); rows 8-15 duplicate 0-7 (always in-bounds)
        const size_t aoff = hb + (size_t)(q0 + (mrow & 7)) * DHEAD + quad * 8;
        short8 ah0 = *(const short8*)(Qhi + aoff);
        short8 ah1 = *(const short8*)(Qhi + aoff + 32);
        short8 al0 = *(const short8*)(Qlo + aoff);
        short8 al1 = *(const short8*)(Qlo + aoff + 32);

        __syncthreads();   // previous head's z-loads complete before overwrite

#pragma unroll 4
        for (int nt = 0; nt < 32; ++nt) {
            const int n0 = w * 512 + nt * 16;
            const size_t boff = hb + (size_t)(n0 + mrow) * DHEAD + quad * 8;
            short8 bh0 = *(const short8*)(Khi + boff);
            short8 bh1 = *(const short8*)(Khi + boff + 32);
            short8 bl0 = *(const short8*)(Klo + boff);
            short8 bl1 = *(const short8*)(Klo + boff + 32);
            f32x4 d = {0.f, 0.f, 0.f, 0.f};
            d = __builtin_amdgcn_mfma_f32_16x16x32_bf16(al0, bh0, d, 0, 0, 0);
            d = __builtin_amdgcn_mfma_f32_16x16x32_bf16(ah0, bl0, d, 0, 0, 0);
            d = __builtin_amdgcn_mfma_f32_16x16x32_bf16(ah0, bh0, d, 0, 0, 0);
            d = __builtin_amdgcn_mfma_f32_16x16x32_bf16(al1, bh1, d, 0, 0, 0);
            d = __builtin_amdgcn_mfma_f32_16x16x32_bf16(ah1, bl1, d, 0, 0, 0);
            d = __builtin_amdgcn_mfma_f32_16x16x32_bf16(ah1, bh1, d, 0, 0, 0);
            if (quad < 2) {           // rows 0..7 only (8..15 are dups)
#pragma unroll
                for (int reg = 0; reg < 4; ++reg)
                    S[(quad * 4 + reg) * 1024 + n0 + mrow] = d[reg];
            }
        }
        __syncthreads();

        // ---- sparsemax: wave w owns rows 4w..4w+3, lockstep; all in regs ----
        {
            float z[4][16];
            float sv[4], mv[4];
#pragma unroll
            for (int rr = 0; rr < 4; ++rr) {
                const int r = w * 4 + rr;
#pragma unroll
                for (int c = 0; c < 4; ++c)
                    *(f32x4*)&z[rr][c * 4] = *(const f32x4*)&S[r * 1024 + c * 256 + lane * 4];
                // tree-structured sum & max (short dep chains)
                float s0 = 0.f, s1 = 0.f, s2 = 0.f, s3 = 0.f;
                float m0 = z[rr][0], m1 = z[rr][1], m2 = z[rr][2], m3 = z[rr][3];
#pragma unroll
                for (int j = 0; j < 4; ++j) {
                    s0 += z[rr][j];      s1 += z[rr][4 + j];
                    s2 += z[rr][8 + j];  s3 += z[rr][12 + j];
                }
#pragma unroll
                for (int j = 4; j < 16; j += 4) {
                    m0 = fmaxf(m0, z[rr][j]);     m1 = fmaxf(m1, z[rr][j + 1]);
                    m2 = fmaxf(m2, z[rr][j + 2]); m3 = fmaxf(m3, z[rr][j + 3]);
                }
                sv[rr] = (s0 + s1) + (s2 + s3);
                mv[rr] = fmaxf(fmaxf(m0, m1), fmaxf(m2, m3));
            }
            wsummax4(sv, mv);

            float tau[4]; int prev[4]; bool done[4];
#pragma unroll
            for (int rr = 0; rr < 4; ++rr) {
                tau[rr] = fmaxf((sv[rr] - 1.0f) * (1.0f / 1024.0f), mv[rr] - 1.0f);
                prev[rr] = -1; done[rr] = false;
            }

            for (int it = 0; it < 48; ++it) {
                float s4[4]; int c4[4];
#pragma unroll
                for (int rr = 0; rr < 4; ++rr) {
                    float s0 = 0.f, s1 = 0.f, s2 = 0.f, s3 = 0.f;
                    int c = 0;
#pragma unroll
                    for (int j = 0; j < 4; ++j) {
                        bool g0 = z[rr][j]      > tau[rr];
                        bool g1 = z[rr][4 + j]  > tau[rr];
                        bool g2 = z[rr][8 + j]  > tau[rr];
                        bool g3 = z[rr][12 + j] > tau[rr];
                        c += __popcll(__ballot(g0)) + __popcll(__ballot(g1))
                           + __popcll(__ballot(g2)) + __popcll(__ballot(g3));
                        s0 += g0 ? z[rr][j]      : 0.f;
                        s1 += g1 ? z[rr][4 + j]  : 0.f;
                        s2 += g2 ? z[rr][8 + j]  : 0.f;
                        s3 += g3 ? z[rr][12 + j] : 0.f;
                    }
                    s4[rr] = (s0 + s1) + (s2 + s3); c4[rr] = c;
                }
                wsum4(s4);
                bool alldone = true;
#pragma unroll
                for (int rr = 0; rr < 4; ++rr) {
                    if (!done[rr]) {
                        if (c4[rr] == prev[rr]) done[rr] = true;
                        else { tau[rr] = (s4[rr] - 1.0f) / (float)c4[rr]; prev[rr] = c4[rr]; }
                    }
                    alldone = alldone && done[rr];
                }
                if (alldone) break;
            }

            // p = max(z - tau, 0) accumulated straight into head-mean regs
#pragma unroll
            for (int rr = 0; rr < 4; ++rr)
#pragma unroll
                for (int c = 0; c < 4; ++c)
#pragma unroll
                    for (int j = 0; j < 4; ++j)
                        acc[rr][c][j] += fmaxf(z[rr][c * 4 + j] - tau[rr], 0.f);
        }
    }

    // final attn write: row q0+4w+rr, cols c*256+lane*4 — coalesced f32x4
    float* ao = attn_out + ((size_t)b * LSEQ + q0 + w * 4) * LSEQ;
#pragma unroll
    for (int rr = 0; rr < 4; ++rr)
#pragma unroll
        for (int c = 0; c < 4; ++c) {
            f32x4 o = acc[rr][c] * (1.0f / 12.0f);
            *(f32x4*)&ao[(size_t)rr * LSEQ + c * 256 + lane * 4] = o;
        }
}

// ---------------------------------------------------------------------------
// out_mfma: out[b] = attn[b] @ v[b] via split-bf16 3-pass MFMA. UNCHANGED.
// ---------------------------------------------------------------------------
__global__ __launch_bounds__(256) void out_mfma(
    const float* __restrict__ attn, const float* __restrict__ v,
    float* __restrict__ out) {
    const int b = blockIdx.z;
    const float* Ab = attn + (size_t)b * LSEQ * LSEQ;
    const float* Vb = v    + (size_t)b * LSEQ * DMODEL;
    float* Cb       = out  + (size_t)b * LSEQ * DMODEL;

    __shared__ unsigned short Ah[128][32], Al[128][32];
    __shared__ unsigned short Bh[128][36], Bl[128][36];   // pad 36: conflict-free 8B rd/wr

    const int t    = threadIdx.x;
    const int lane = t & 63;
    const int w    = t >> 6;
    const int wr   = w >> 1, wc = w & 1;
    const int mrow = lane & 15, quad = lane >> 4;
    const int m0   = blockIdx.y * 128;
    const int n0   = blockIdx.x * 128;

    const int srow = t >> 3;
    const int scol = (t & 7) * 4;
    const int bn   = t & 127;
    const int bk0  = (t >> 7) * 16;

    f32x4 acc[4][4];
#pragma unroll
    for (int i = 0; i < 4; ++i)
#pragma unroll
        for (int j = 0; j < 4; ++j) acc[i][j] = (f32x4){0.f, 0.f, 0.f, 0.f};

    for (int k0 = 0; k0 < LSEQ; k0 += 32) {
        float4 av[4];
#pragma unroll
        for (int i = 0; i < 4; ++i)
            av[i] = *(const float4*)&Ab[(size_t)(m0 + srow + i * 32) * LSEQ + k0 + scol];
        float bv[16];
#pragma unroll
        for (int i = 0; i < 16; ++i)
            bv[i] = Vb[(size_t)(k0 + bk0 + i) * DMODEL + n0 + bn];

        __syncthreads();
#pragma unroll
        for (int i = 0; i < 4; ++i) {
            ushort4 h4, l4;
            split2(av[i].x, h4.x, l4.x); split2(av[i].y, h4.y, l4.y);
            split2(av[i].z, h4.z, l4.z); split2(av[i].w, h4.w, l4.w);
            *(ushort4*)&Ah[srow + i * 32][scol] = h4;
            *(ushort4*)&Al[srow + i * 32][scol] = l4;
        }
#pragma unroll
        for (int g = 0; g < 4; ++g) {
            ushort4 h4, l4;
            split2(bv[g * 4 + 0], h4.x, l4.x); split2(bv[g * 4 + 1], h4.y, l4.y);
            split2(bv[g * 4 + 2], h4.z, l4.z); split2(bv[g * 4 + 3], h4.w, l4.w);
            *(ushort4*)&Bh[bn][bk0 + g * 4] = h4;
            *(ushort4*)&Bl[bn][bk0 + g * 4] = l4;
        }
        __syncthreads();

        short8 ah[4], al[4], bh[4], bl[4];
#pragma unroll
        for (int i = 0; i < 4; ++i) {
            ah[i] = *(const short8*)&Ah[wr * 64 + i * 16 + mrow][quad * 8];
            al[i] = *(const short8*)&Al[wr * 64 + i * 16 + mrow][quad * 8];
        }
#pragma unroll
        for (int j = 0; j < 4; ++j) {
            const unsigned short* ph = &Bh[wc * 64 + j * 16 + mrow][quad * 8];
            const unsigned short* pl = &Bl[wc * 64 + j * 16 + mrow][quad * 8];
            uint2 h0 = *(const uint2*)ph;
            uint2 h1 = *(const uint2*)(ph + 4);
            uint2 l0 = *(const uint2*)pl;
            uint2 l1 = *(const uint2*)(pl + 4);
            union { uint u[4]; short8 s; } ch, cl;
            ch.u[0] = h0.x; ch.u[1] = h0.y; ch.u[2] = h1.x; ch.u[3] = h1.y;
            cl.u[0] = l0.x; cl.u[1] = l0.y; cl.u[2] = l1.x; cl.u[3] = l1.y;
            bh[j] = ch.s; bl[j] = cl.s;
        }
#pragma unroll
        for (int i = 0; i < 4; ++i)
#pragma unroll
            for (int j = 0; j < 4; ++j) {
                acc[i][j] = __builtin_amdgcn_mfma_f32_16x16x32_bf16(al[i], bh[j], acc[i][j], 0, 0, 0);
                acc[i][j] = __builtin_amdgcn_mfma_f32_16x16x32_bf16(ah[i], bl[j], acc[i][j], 0, 0, 0);
                acc[i][j] = __builtin_amdgcn_mfma_f32_16x16x32_bf16(ah[i], bh[j], acc[i][j], 0, 0, 0);
            }
    }

#pragma unroll
    for (int i = 0; i < 4; ++i)
#pragma unroll
        for (int j = 0; j < 4; ++j)
#pragma unroll
            for (int reg = 0; reg < 4; ++reg) {
                const int mg = m0 + wr * 64 + i * 16 + quad * 4 + reg;
                const int ng = n0 + wc * 64 + j * 16 + mrow;
                Cb[(size_t)mg * DMODEL + ng] = acc[i][j][reg];
            }
}

extern "C" void kernel_launch(void* const* d_in, const int* in_sizes, int n_in,
                              void* d_out, int out_size, void* d_ws, size_t ws_size,
                              hipStream_t stream) {
    const float* q  = (const float*)d_in[0];
    const float* k  = (const float*)d_in[1];
    const float* v  = (const float*)d_in[2];
    const float* Wq = (const float*)d_in[3];
    const float* bq = (const float*)d_in[4];
    const float* Wk = (const float*)d_in[5];
    const float* bk = (const float*)d_in[6];

    float* out  = (float*)d_out;                 // [8,1024,768]
    float* attn = out + OUT_ELEMS;               // [8,1024,1024]
    unsigned short* ws = (unsigned short*)d_ws;  // Qhi|Qlo|Khi|Klo bf16 planes (50 MB)

    hipLaunchKernelGGL(proj_mfma, dim3(6, 64, 2), dim3(256), 0, stream,
                       q, k, Wq, bq, Wk, bk, ws);
    hipLaunchKernelGGL(attn_kernel, dim3(128, 8), dim3(128), 0, stream,
                       ws, attn);
    hipLaunchKernelGGL(out_mfma, dim3(6, 8, 8), dim3(256), 0, stream,
                       attn, v, out);
}

// Round 6
// 722.094 us; speedup vs baseline: 1.0892x; 1.0892x over previous
//
#include <hip/hip_runtime.h>

// Problem constants
#define BSZ 8
#define NH 12
#define LSEQ 1024
#define DMODEL 768
#define DHEAD 64
#define OUT_ELEMS 6291456   // 8*1024*768
#define ATTN_ELEMS 8388608  // 8*1024*1024

typedef __attribute__((ext_vector_type(8))) short short8;   // 8 x bf16 (4 VGPRs)
typedef __attribute__((ext_vector_type(4))) float f32x4;

__device__ __forceinline__ int   f2i(float x) { union { float f; int i; } c; c.f = x; return c.i; }
__device__ __forceinline__ float i2f(int x)   { union { int i; float f; } c; c.i = x; return c.f; }

__device__ __forceinline__ unsigned short f2bf(float x) {
    union { float f; unsigned u; } c; c.f = x;
    unsigned r = (c.u + 0x7FFF + ((c.u >> 16) & 1)) >> 16;   // RNE
    return (unsigned short)r;
}
__device__ __forceinline__ float bf2f(unsigned short h) {
    union { float f; unsigned u; } c; c.u = ((unsigned)h) << 16;
    return c.f;
}
__device__ __forceinline__ void split2(float x, unsigned short& h, unsigned short& l) {
    h = f2bf(x);
    l = f2bf(x - bf2f(h));
}

// ---- DPP wave-64 reductions, N interleaved chains, result broadcast ----
template<int CTRL>
__device__ __forceinline__ float dppadd(float v) {
    return v + i2f(__builtin_amdgcn_update_dpp(0, f2i(v), CTRL, 0xF, 0xF, true));
}
template<int CTRL>
__device__ __forceinline__ float dppmax(float v) {
    return fmaxf(v, i2f(__builtin_amdgcn_update_dpp(f2i(v), f2i(v), CTRL, 0xF, 0xF, false)));
}

template<int N>
__device__ __forceinline__ void wsumN(float* s) {
#define WS(CTRL) _Pragma("unroll") for (int rr = 0; rr < N; ++rr) { s[rr] = dppadd<CTRL>(s[rr]); }
    WS(0x111) WS(0x112) WS(0x114) WS(0x118) WS(0x142) WS(0x143)
#undef WS
#pragma unroll
    for (int rr = 0; rr < N; ++rr) s[rr] = i2f(__builtin_amdgcn_readlane(f2i(s[rr]), 63));
}

template<int N>
__device__ __forceinline__ void wsummaxN(float* s, float* m) {
#define WS(CTRL) _Pragma("unroll") for (int rr = 0; rr < N; ++rr) { s[rr] = dppadd<CTRL>(s[rr]); m[rr] = dppmax<CTRL>(m[rr]); }
    WS(0x111) WS(0x112) WS(0x114) WS(0x118) WS(0x142) WS(0x143)
#undef WS
#pragma unroll
    for (int rr = 0; rr < N; ++rr) {
        s[rr] = i2f(__builtin_amdgcn_readlane(f2i(s[rr]), 63));
        m[rr] = i2f(__builtin_amdgcn_readlane(f2i(m[rr]), 63));
    }
}

// ---------------------------------------------------------------------------
// proj_mfma: C = A @ W^T + bias via split-bf16 3-pass MFMA.
// Q path pre-scaled by 0.125 (1/sqrt(DHEAD)) — exact power-of-2 fold.
// ---------------------------------------------------------------------------
__global__ __launch_bounds__(256) void proj_mfma(
    const float* __restrict__ qin, const float* __restrict__ kin,
    const float* __restrict__ Wq, const float* __restrict__ bq,
    const float* __restrict__ Wk, const float* __restrict__ bk,
    unsigned short* __restrict__ ws) {
    const float* A; const float* W; const float* bias;
    unsigned short* hi; unsigned short* lo;
    if (blockIdx.z == 0) { A = qin; W = Wq; bias = bq; hi = ws;                lo = ws + OUT_ELEMS; }
    else                 { A = kin; W = Wk; bias = bk; hi = ws + 2*OUT_ELEMS; lo = ws + 3*OUT_ELEMS; }
    const float oscale = (blockIdx.z == 0) ? 0.125f : 1.0f;

    __shared__ unsigned short Ah[128][32], Al[128][32];
    __shared__ unsigned short Bh[128][32], Bl[128][32];

    const int t    = threadIdx.x;
    const int lane = t & 63;
    const int w    = t >> 6;
    const int wr   = w >> 1, wc = w & 1;
    const int mrow = lane & 15, quad = lane >> 4;
    const int m0   = blockIdx.y * 128;
    const int n0   = blockIdx.x * 128;

    const int srow = t >> 3;
    const int scol = (t & 7) * 4;

    f32x4 acc[4][4];
#pragma unroll
    for (int i = 0; i < 4; ++i)
#pragma unroll
        for (int j = 0; j < 4; ++j) acc[i][j] = (f32x4){0.f, 0.f, 0.f, 0.f};

    for (int k0 = 0; k0 < DMODEL; k0 += 32) {
        float4 av[4], wv[4];
#pragma unroll
        for (int i = 0; i < 4; ++i) {
            av[i] = *(const float4*)&A[(size_t)(m0 + srow + i * 32) * DMODEL + k0 + scol];
            wv[i] = *(const float4*)&W[(size_t)(n0 + srow + i * 32) * DMODEL + k0 + scol];
        }
        __syncthreads();
#pragma unroll
        for (int i = 0; i < 4; ++i) {
            ushort4 h4, l4;
            split2(av[i].x, h4.x, l4.x); split2(av[i].y, h4.y, l4.y);
            split2(av[i].z, h4.z, l4.z); split2(av[i].w, h4.w, l4.w);
            *(ushort4*)&Ah[srow + i * 32][scol] = h4;
            *(ushort4*)&Al[srow + i * 32][scol] = l4;
            split2(wv[i].x, h4.x, l4.x); split2(wv[i].y, h4.y, l4.y);
            split2(wv[i].z, h4.z, l4.z); split2(wv[i].w, h4.w, l4.w);
            *(ushort4*)&Bh[srow + i * 32][scol] = h4;
            *(ushort4*)&Bl[srow + i * 32][scol] = l4;
        }
        __syncthreads();

        short8 ah[4], al[4], bh[4], bl[4];
#pragma unroll
        for (int i = 0; i < 4; ++i) {
            ah[i] = *(const short8*)&Ah[wr * 64 + i * 16 + mrow][quad * 8];
            al[i] = *(const short8*)&Al[wr * 64 + i * 16 + mrow][quad * 8];
            bh[i] = *(const short8*)&Bh[wc * 64 + i * 16 + mrow][quad * 8];
            bl[i] = *(const short8*)&Bl[wc * 64 + i * 16 + mrow][quad * 8];
        }
#pragma unroll
        for (int i = 0; i < 4; ++i)
#pragma unroll
            for (int j = 0; j < 4; ++j) {
                acc[i][j] = __builtin_amdgcn_mfma_f32_16x16x32_bf16(al[i], bh[j], acc[i][j], 0, 0, 0);
                acc[i][j] = __builtin_amdgcn_mfma_f32_16x16x32_bf16(ah[i], bl[j], acc[i][j], 0, 0, 0);
                acc[i][j] = __builtin_amdgcn_mfma_f32_16x16x32_bf16(ah[i], bh[j], acc[i][j], 0, 0, 0);
            }
    }

#pragma unroll
    for (int j = 0; j < 4; ++j) {
        const int ng = n0 + wc * 64 + j * 16 + mrow;
        const float bj = bias[ng];
        const int hh = ng >> 6, dd = ng & 63;
#pragma unroll
        for (int i = 0; i < 4; ++i) {
#pragma unroll
            for (int reg = 0; reg < 4; ++reg) {
                const int mg = m0 + wr * 64 + i * 16 + quad * 4 + reg;
                const float c = (acc[i][j][reg] + bj) * oscale;
                unsigned short ch, cl;
                split2(c, ch, cl);
                const size_t idx = (((size_t)(mg >> 10) * NH + hh) * LSEQ + (mg & 1023)) * DHEAD + dd;
                hi[idx] = ch;
                lo[idx] = cl;
            }
        }
    }
}

// ---------------------------------------------------------------------------
// Fused scores + sparsemax + head-mean.
// R6: R4 shape (256 thr, 16 q-rows, 64 KB S, 512 blocks). Heads processed in
// PAIRS: stage scores h then h+1, keep z for both in regs, then run 8
// interleaved Michelot chains (2 heads x 4 rows) — 2x ILP on all latency
// chains. MFMA per tile split into two independent 3-chains (d0,d1).
// ---------------------------------------------------------------------------
__global__ __launch_bounds__(256) void attn_kernel(
    const unsigned short* __restrict__ ws, float* __restrict__ attn_out) {
    __shared__ float S[16 * 1024];    // 64 KB score tile

    const unsigned short* Qhi = ws;
    const unsigned short* Qlo = ws + OUT_ELEMS;
    const unsigned short* Khi = ws + 2 * OUT_ELEMS;
    const unsigned short* Klo = ws + 3 * OUT_ELEMS;

    const int t = threadIdx.x;
    const int lane = t & 63;
    const int w = t >> 6;             // wave 0..3
    const int b = blockIdx.y;
    const int q0 = blockIdx.x * 16;

    const int mrow = lane & 15;
    const int quad = lane >> 4;

    f32x4 acc[4][4];                  // head-mean partials [row rr][col grp c]
#pragma unroll
    for (int rr = 0; rr < 4; ++rr)
#pragma unroll
        for (int c = 0; c < 4; ++c) acc[rr][c] = (f32x4){0.f, 0.f, 0.f, 0.f};

    float z[8][16];                   // 2 heads x 4 rows x 16 cols/lane
    float sv[8], mv[8], tau[8];
    int prev[8]; bool done[8];

    for (int hp = 0; hp < NH / 2; ++hp) {
#pragma unroll
        for (int sub = 0; sub < 2; ++sub) {
            const int h = hp * 2 + sub;
            const size_t hb = ((size_t)b * NH + h) * (LSEQ * DHEAD);

            // A fragments for this head
            const size_t aoff = hb + (size_t)(q0 + mrow) * DHEAD + quad * 8;
            short8 ah0 = *(const short8*)(Qhi + aoff);
            short8 ah1 = *(const short8*)(Qhi + aoff + 32);
            short8 al0 = *(const short8*)(Qlo + aoff);
            short8 al1 = *(const short8*)(Qlo + aoff + 32);

            __syncthreads();   // prior z-loads complete before S overwrite

#pragma unroll 4
            for (int nt = 0; nt < 16; ++nt) {
                const int n0 = w * 256 + nt * 16;
                const size_t boff = hb + (size_t)(n0 + mrow) * DHEAD + quad * 8;
                short8 bh0 = *(const short8*)(Khi + boff);
                short8 bh1 = *(const short8*)(Khi + boff + 32);
                short8 bl0 = *(const short8*)(Klo + boff);
                short8 bl1 = *(const short8*)(Klo + boff + 32);
                // two independent 3-deep chains (k-halves), summed at the end
                f32x4 d0 = {0.f, 0.f, 0.f, 0.f};
                f32x4 d1 = {0.f, 0.f, 0.f, 0.f};
                d0 = __builtin_amdgcn_mfma_f32_16x16x32_bf16(al0, bh0, d0, 0, 0, 0);
                d1 = __builtin_amdgcn_mfma_f32_16x16x32_bf16(al1, bh1, d1, 0, 0, 0);
                d0 = __builtin_amdgcn_mfma_f32_16x16x32_bf16(ah0, bl0, d0, 0, 0, 0);
                d1 = __builtin_amdgcn_mfma_f32_16x16x32_bf16(ah1, bl1, d1, 0, 0, 0);
                d0 = __builtin_amdgcn_mfma_f32_16x16x32_bf16(ah0, bh0, d0, 0, 0, 0);
                d1 = __builtin_amdgcn_mfma_f32_16x16x32_bf16(ah1, bh1, d1, 0, 0, 0);
#pragma unroll
                for (int reg = 0; reg < 4; ++reg)
                    S[(quad * 4 + reg) * 1024 + n0 + mrow] = d0[reg] + d1[reg];
            }
            __syncthreads();

            // z-load for this head into chains sub*4 .. sub*4+3
#pragma unroll
            for (int rr = 0; rr < 4; ++rr) {
                const int ci = sub * 4 + rr;
                const int r = w * 4 + rr;
#pragma unroll
                for (int c = 0; c < 4; ++c)
                    *(f32x4*)&z[ci][c * 4] = *(const f32x4*)&S[r * 1024 + c * 256 + lane * 4];
                float s0 = 0.f, s1 = 0.f, s2 = 0.f, s3 = 0.f;
                float m0 = z[ci][0], m1 = z[ci][1], m2 = z[ci][2], m3 = z[ci][3];
#pragma unroll
                for (int j = 0; j < 4; ++j) {
                    s0 += z[ci][j];      s1 += z[ci][4 + j];
                    s2 += z[ci][8 + j];  s3 += z[ci][12 + j];
                }
#pragma unroll
                for (int j = 4; j < 16; j += 4) {
                    m0 = fmaxf(m0, z[ci][j]);     m1 = fmaxf(m1, z[ci][j + 1]);
                    m2 = fmaxf(m2, z[ci][j + 2]); m3 = fmaxf(m3, z[ci][j + 3]);
                }
                sv[ci] = (s0 + s1) + (s2 + s3);
                mv[ci] = fmaxf(fmaxf(m0, m1), fmaxf(m2, m3));
            }
        }

        // ---- 8 interleaved Michelot chains (2 heads x 4 rows) ----
        wsummaxN<8>(sv, mv);
#pragma unroll
        for (int ci = 0; ci < 8; ++ci) {
            tau[ci] = fmaxf((sv[ci] - 1.0f) * (1.0f / 1024.0f), mv[ci] - 1.0f);
            prev[ci] = -1; done[ci] = false;
        }

        for (int it = 0; it < 48; ++it) {
            float s8[8]; int c8[8];
#pragma unroll
            for (int ci = 0; ci < 8; ++ci) {
                if (done[ci]) { s8[ci] = 0.f; c8[ci] = prev[ci]; continue; }  // uniform skip
                float s0 = 0.f, s1 = 0.f, s2 = 0.f, s3 = 0.f;
                int c = 0;
#pragma unroll
                for (int j = 0; j < 4; ++j) {
                    bool g0 = z[ci][j]      > tau[ci];
                    bool g1 = z[ci][4 + j]  > tau[ci];
                    bool g2 = z[ci][8 + j]  > tau[ci];
                    bool g3 = z[ci][12 + j] > tau[ci];
                    c += __popcll(__ballot(g0)) + __popcll(__ballot(g1))
                       + __popcll(__ballot(g2)) + __popcll(__ballot(g3));
                    s0 += g0 ? z[ci][j]      : 0.f;
                    s1 += g1 ? z[ci][4 + j]  : 0.f;
                    s2 += g2 ? z[ci][8 + j]  : 0.f;
                    s3 += g3 ? z[ci][12 + j] : 0.f;
                }
                s8[ci] = (s0 + s1) + (s2 + s3); c8[ci] = c;
            }
            wsumN<8>(s8);
            bool alldone = true;
#pragma unroll
            for (int ci = 0; ci < 8; ++ci) {
                if (!done[ci]) {
                    if (c8[ci] == prev[ci]) done[ci] = true;
                    else { tau[ci] = (s8[ci] - 1.0f) / (float)c8[ci]; prev[ci] = c8[ci]; }
                }
                alldone = alldone && done[ci];
            }
            if (alldone) break;
        }

        // p = max(z - tau, 0), both heads, straight into head-mean regs
#pragma unroll
        for (int rr = 0; rr < 4; ++rr)
#pragma unroll
            for (int c = 0; c < 4; ++c)
#pragma unroll
                for (int j = 0; j < 4; ++j)
                    acc[rr][c][j] += fmaxf(z[rr][c * 4 + j] - tau[rr], 0.f)
                                   + fmaxf(z[4 + rr][c * 4 + j] - tau[4 + rr], 0.f);
    }

    // final attn write: row q0+4w+rr, cols c*256+lane*4 — coalesced f32x4
    float* ao = attn_out + ((size_t)b * LSEQ + q0 + w * 4) * LSEQ;
#pragma unroll
    for (int rr = 0; rr < 4; ++rr)
#pragma unroll
        for (int c = 0; c < 4; ++c) {
            f32x4 o = acc[rr][c] * (1.0f / 12.0f);
            *(f32x4*)&ao[(size_t)rr * LSEQ + c * 256 + lane * 4] = o;
        }
}

// ---------------------------------------------------------------------------
// out_mfma: out[b] = attn[b] @ v[b] via split-bf16 3-pass MFMA. UNCHANGED.
// ---------------------------------------------------------------------------
__global__ __launch_bounds__(256) void out_mfma(
    const float* __restrict__ attn, const float* __restrict__ v,
    float* __restrict__ out) {
    const int b = blockIdx.z;
    const float* Ab = attn + (size_t)b * LSEQ * LSEQ;
    const float* Vb = v    + (size_t)b * LSEQ * DMODEL;
    float* Cb       = out  + (size_t)b * LSEQ * DMODEL;

    __shared__ unsigned short Ah[128][32], Al[128][32];
    __shared__ unsigned short Bh[128][36], Bl[128][36];   // pad 36: conflict-free 8B rd/wr

    const int t    = threadIdx.x;
    const int lane = t & 63;
    const int w    = t >> 6;
    const int wr   = w >> 1, wc = w & 1;
    const int mrow = lane & 15, quad = lane >> 4;
    const int m0   = blockIdx.y * 128;
    const int n0   = blockIdx.x * 128;

    const int srow = t >> 3;
    const int scol = (t & 7) * 4;
    const int bn   = t & 127;
    const int bk0  = (t >> 7) * 16;

    f32x4 acc[4][4];
#pragma unroll
    for (int i = 0; i < 4; ++i)
#pragma unroll
        for (int j = 0; j < 4; ++j) acc[i][j] = (f32x4){0.f, 0.f, 0.f, 0.f};

    for (int k0 = 0; k0 < LSEQ; k0 += 32) {
        float4 av[4];
#pragma unroll
        for (int i = 0; i < 4; ++i)
            av[i] = *(const float4*)&Ab[(size_t)(m0 + srow + i * 32) * LSEQ + k0 + scol];
        float bv[16];
#pragma unroll
        for (int i = 0; i < 16; ++i)
            bv[i] = Vb[(size_t)(k0 + bk0 + i) * DMODEL + n0 + bn];

        __syncthreads();
#pragma unroll
        for (int i = 0; i < 4; ++i) {
            ushort4 h4, l4;
            split2(av[i].x, h4.x, l4.x); split2(av[i].y, h4.y, l4.y);
            split2(av[i].z, h4.z, l4.z); split2(av[i].w, h4.w, l4.w);
            *(ushort4*)&Ah[srow + i * 32][scol] = h4;
            *(ushort4*)&Al[srow + i * 32][scol] = l4;
        }
#pragma unroll
        for (int g = 0; g < 4; ++g) {
            ushort4 h4, l4;
            split2(bv[g * 4 + 0], h4.x, l4.x); split2(bv[g * 4 + 1], h4.y, l4.y);
            split2(bv[g * 4 + 2], h4.z, l4.z); split2(bv[g * 4 + 3], h4.w, l4.w);
            *(ushort4*)&Bh[bn][bk0 + g * 4] = h4;
            *(ushort4*)&Bl[bn][bk0 + g * 4] = l4;
        }
        __syncthreads();

        short8 ah[4], al[4], bh[4], bl[4];
#pragma unroll
        for (int i = 0; i < 4; ++i) {
            ah[i] = *(const short8*)&Ah[wr * 64 + i * 16 + mrow][quad * 8];
            al[i] = *(const short8*)&Al[wr * 64 + i * 16 + mrow][quad * 8];
        }
#pragma unroll
        for (int j = 0; j < 4; ++j) {
            const unsigned short* ph = &Bh[wc * 64 + j * 16 + mrow][quad * 8];
            const unsigned short* pl = &Bl[wc * 64 + j * 16 + mrow][quad * 8];
            uint2 h0 = *(const uint2*)ph;
            uint2 h1 = *(const uint2*)(ph + 4);
            uint2 l0 = *(const uint2*)pl;
            uint2 l1 = *(const uint2*)(pl + 4);
            union { uint u[4]; short8 s; } ch, cl;
            ch.u[0] = h0.x; ch.u[1] = h0.y; ch.u[2] = h1.x; ch.u[3] = h1.y;
            cl.u[0] = l0.x; cl.u[1] = l0.y; cl.u[2] = l1.x; cl.u[3] = l1.y;
            bh[j] = ch.s; bl[j] = cl.s;
        }
#pragma unroll
        for (int i = 0; i < 4; ++i)
#pragma unroll
            for (int j = 0; j < 4; ++j) {
                acc[i][j] = __builtin_amdgcn_mfma_f32_16x16x32_bf16(al[i], bh[j], acc[i][j], 0, 0, 0);
                acc[i][j] = __builtin_amdgcn_mfma_f32_16x16x32_bf16(ah[i], bl[j], acc[i][j], 0, 0, 0);
                acc[i][j] = __builtin_amdgcn_mfma_f32_16x16x32_bf16(ah[i], bh[j], acc[i][j], 0, 0, 0);
            }
    }

#pragma unroll
    for (int i = 0; i < 4; ++i)
#pragma unroll
        for (int j = 0; j < 4; ++j)
#pragma unroll
            for (int reg = 0; reg < 4; ++reg) {
                const int mg = m0 + wr * 64 + i * 16 + quad * 4 + reg;
                const int ng = n0 + wc * 64 + j * 16 + mrow;
                Cb[(size_t)mg * DMODEL + ng] = acc[i][j][reg];
            }
}

extern "C" void kernel_launch(void* const* d_in, const int* in_sizes, int n_in,
                              void* d_out, int out_size, void* d_ws, size_t ws_size,
                              hipStream_t stream) {
    const float* q  = (const float*)d_in[0];
    const float* k  = (const float*)d_in[1];
    const float* v  = (const float*)d_in[2];
    const float* Wq = (const float*)d_in[3];
    const float* bq = (const float*)d_in[4];
    const float* Wk = (const float*)d_in[5];
    const float* bk = (const float*)d_in[6];

    float* out  = (float*)d_out;                 // [8,1024,768]
    float* attn = out + OUT_ELEMS;               // [8,1024,1024]
    unsigned short* ws = (unsigned short*)d_ws;  // Qhi|Qlo|Khi|Klo bf16 planes (50 MB)

    hipLaunchKernelGGL(proj_mfma, dim3(6, 64, 2), dim3(256), 0, stream,
                       q, k, Wq, bq, Wk, bk, ws);
    hipLaunchKernelGGL(attn_kernel, dim3(64, 8), dim3(256), 0, stream,
                       ws, attn);
    hipLaunchKernelGGL(out_mfma, dim3(6, 8, 8), dim3(256), 0, stream,
                       attn, v, out);
}

// Round 7
// 630.704 us; speedup vs baseline: 1.2470x; 1.1449x over previous
//
#include <hip/hip_runtime.h>

// Problem constants
#define BSZ 8
#define NH 12
#define LSEQ 1024
#define DMODEL 768
#define DHEAD 64
#define OUT_ELEMS 6291456   // 8*1024*768
#define ATTN_ELEMS 8388608  // 8*1024*1024

typedef __attribute__((ext_vector_type(8))) short short8;   // 8 x bf16 (4 VGPRs)
typedef __attribute__((ext_vector_type(4))) float f32x4;

__device__ __forceinline__ int   f2i(float x) { union { float f; int i; } c; c.f = x; return c.i; }
__device__ __forceinline__ float i2f(int x)   { union { int i; float f; } c; c.i = x; return c.f; }

__device__ __forceinline__ unsigned short f2bf(float x) {
    union { float f; unsigned u; } c; c.f = x;
    unsigned r = (c.u + 0x7FFF + ((c.u >> 16) & 1)) >> 16;   // RNE
    return (unsigned short)r;
}
__device__ __forceinline__ float bf2f(unsigned short h) {
    union { float f; unsigned u; } c; c.u = ((unsigned)h) << 16;
    return c.f;
}
__device__ __forceinline__ void split2(float x, unsigned short& h, unsigned short& l) {
    h = f2bf(x);
    l = f2bf(x - bf2f(h));
}

// ---- DPP wave-64 reductions, N interleaved chains, result broadcast ----
template<int CTRL>
__device__ __forceinline__ float dppadd(float v) {
    return v + i2f(__builtin_amdgcn_update_dpp(0, f2i(v), CTRL, 0xF, 0xF, true));
}
template<int CTRL>
__device__ __forceinline__ float dppmax(float v) {
    return fmaxf(v, i2f(__builtin_amdgcn_update_dpp(f2i(v), f2i(v), CTRL, 0xF, 0xF, false)));
}

template<int N>
__device__ __forceinline__ void wsumN(float* s) {
#define WS(CTRL) _Pragma("unroll") for (int rr = 0; rr < N; ++rr) { s[rr] = dppadd<CTRL>(s[rr]); }
    WS(0x111) WS(0x112) WS(0x114) WS(0x118) WS(0x142) WS(0x143)
#undef WS
#pragma unroll
    for (int rr = 0; rr < N; ++rr) s[rr] = i2f(__builtin_amdgcn_readlane(f2i(s[rr]), 63));
}

template<int N>
__device__ __forceinline__ void wsummaxN(float* s, float* m) {
#define WS(CTRL) _Pragma("unroll") for (int rr = 0; rr < N; ++rr) { s[rr] = dppadd<CTRL>(s[rr]); m[rr] = dppmax<CTRL>(m[rr]); }
    WS(0x111) WS(0x112) WS(0x114) WS(0x118) WS(0x142) WS(0x143)
#undef WS
#pragma unroll
    for (int rr = 0; rr < N; ++rr) {
        s[rr] = i2f(__builtin_amdgcn_readlane(f2i(s[rr]), 63));
        m[rr] = i2f(__builtin_amdgcn_readlane(f2i(m[rr]), 63));
    }
}

// ---------------------------------------------------------------------------
// proj_mfma: C = A @ W^T + bias via split-bf16 3-pass MFMA. UNCHANGED (R5).
// Q path pre-scaled by 0.125 (1/sqrt(DHEAD)) — exact power-of-2 fold.
// ---------------------------------------------------------------------------
__global__ __launch_bounds__(256) void proj_mfma(
    const float* __restrict__ qin, const float* __restrict__ kin,
    const float* __restrict__ Wq, const float* __restrict__ bq,
    const float* __restrict__ Wk, const float* __restrict__ bk,
    unsigned short* __restrict__ ws) {
    const float* A; const float* W; const float* bias;
    unsigned short* hi; unsigned short* lo;
    if (blockIdx.z == 0) { A = qin; W = Wq; bias = bq; hi = ws;                lo = ws + OUT_ELEMS; }
    else                 { A = kin; W = Wk; bias = bk; hi = ws + 2*OUT_ELEMS; lo = ws + 3*OUT_ELEMS; }
    const float oscale = (blockIdx.z == 0) ? 0.125f : 1.0f;

    __shared__ unsigned short Ah[128][32], Al[128][32];
    __shared__ unsigned short Bh[128][32], Bl[128][32];

    const int t    = threadIdx.x;
    const int lane = t & 63;
    const int w    = t >> 6;
    const int wr   = w >> 1, wc = w & 1;
    const int mrow = lane & 15, quad = lane >> 4;
    const int m0   = blockIdx.y * 128;
    const int n0   = blockIdx.x * 128;

    const int srow = t >> 3;
    const int scol = (t & 7) * 4;

    f32x4 acc[4][4];
#pragma unroll
    for (int i = 0; i < 4; ++i)
#pragma unroll
        for (int j = 0; j < 4; ++j) acc[i][j] = (f32x4){0.f, 0.f, 0.f, 0.f};

    for (int k0 = 0; k0 < DMODEL; k0 += 32) {
        float4 av[4], wv[4];
#pragma unroll
        for (int i = 0; i < 4; ++i) {
            av[i] = *(const float4*)&A[(size_t)(m0 + srow + i * 32) * DMODEL + k0 + scol];
            wv[i] = *(const float4*)&W[(size_t)(n0 + srow + i * 32) * DMODEL + k0 + scol];
        }
        __syncthreads();
#pragma unroll
        for (int i = 0; i < 4; ++i) {
            ushort4 h4, l4;
            split2(av[i].x, h4.x, l4.x); split2(av[i].y, h4.y, l4.y);
            split2(av[i].z, h4.z, l4.z); split2(av[i].w, h4.w, l4.w);
            *(ushort4*)&Ah[srow + i * 32][scol] = h4;
            *(ushort4*)&Al[srow + i * 32][scol] = l4;
            split2(wv[i].x, h4.x, l4.x); split2(wv[i].y, h4.y, l4.y);
            split2(wv[i].z, h4.z, l4.z); split2(wv[i].w, h4.w, l4.w);
            *(ushort4*)&Bh[srow + i * 32][scol] = h4;
            *(ushort4*)&Bl[srow + i * 32][scol] = l4;
        }
        __syncthreads();

        short8 ah[4], al[4], bh[4], bl[4];
#pragma unroll
        for (int i = 0; i < 4; ++i) {
            ah[i] = *(const short8*)&Ah[wr * 64 + i * 16 + mrow][quad * 8];
            al[i] = *(const short8*)&Al[wr * 64 + i * 16 + mrow][quad * 8];
            bh[i] = *(const short8*)&Bh[wc * 64 + i * 16 + mrow][quad * 8];
            bl[i] = *(const short8*)&Bl[wc * 64 + i * 16 + mrow][quad * 8];
        }
#pragma unroll
        for (int i = 0; i < 4; ++i)
#pragma unroll
            for (int j = 0; j < 4; ++j) {
                acc[i][j] = __builtin_amdgcn_mfma_f32_16x16x32_bf16(al[i], bh[j], acc[i][j], 0, 0, 0);
                acc[i][j] = __builtin_amdgcn_mfma_f32_16x16x32_bf16(ah[i], bl[j], acc[i][j], 0, 0, 0);
                acc[i][j] = __builtin_amdgcn_mfma_f32_16x16x32_bf16(ah[i], bh[j], acc[i][j], 0, 0, 0);
            }
    }

#pragma unroll
    for (int j = 0; j < 4; ++j) {
        const int ng = n0 + wc * 64 + j * 16 + mrow;
        const float bj = bias[ng];
        const int hh = ng >> 6, dd = ng & 63;
#pragma unroll
        for (int i = 0; i < 4; ++i) {
#pragma unroll
            for (int reg = 0; reg < 4; ++reg) {
                const int mg = m0 + wr * 64 + i * 16 + quad * 4 + reg;
                const float c = (acc[i][j][reg] + bj) * oscale;
                unsigned short ch, cl;
                split2(c, ch, cl);
                const size_t idx = (((size_t)(mg >> 10) * NH + hh) * LSEQ + (mg & 1023)) * DHEAD + dd;
                hi[idx] = ch;
                lo[idx] = cl;
            }
        }
    }
}

// ---------------------------------------------------------------------------
// score_kernel: Sg[bh, q-qbase, :] = Qh[bh] @ Kh[bh]^T for 16 q-rows.
// No LDS, no barriers — D-regs stored straight to global. Store-bound.
// Grid: (CQ/16, B*NH). Block 256 (4 waves; wave w owns 256-col strip).
// ---------------------------------------------------------------------------
__global__ __launch_bounds__(256) void score_kernel(
    const unsigned short* __restrict__ ws, float* __restrict__ Sg,
    int qbase, int CQ) {
    const unsigned short* Qhi = ws;
    const unsigned short* Qlo = ws + OUT_ELEMS;
    const unsigned short* Khi = ws + 2 * OUT_ELEMS;
    const unsigned short* Klo = ws + 3 * OUT_ELEMS;

    const int t = threadIdx.x;
    const int lane = t & 63;
    const int w = t >> 6;
    const int bh = blockIdx.y;
    const int q0r = blockIdx.x * 16;           // chunk-relative
    const int q0 = qbase + q0r;                // absolute

    const int mrow = lane & 15;
    const int quad = lane >> 4;

    const size_t hb = (size_t)bh * (LSEQ * DHEAD);
    const size_t aoff = hb + (size_t)(q0 + mrow) * DHEAD + quad * 8;
    short8 ah0 = *(const short8*)(Qhi + aoff);
    short8 ah1 = *(const short8*)(Qhi + aoff + 32);
    short8 al0 = *(const short8*)(Qlo + aoff);
    short8 al1 = *(const short8*)(Qlo + aoff + 32);

    float* Sb = Sg + ((size_t)bh * CQ + q0r) * LSEQ;

#pragma unroll 4
    for (int nt = 0; nt < 16; ++nt) {
        const int n0 = w * 256 + nt * 16;
        const size_t boff = hb + (size_t)(n0 + mrow) * DHEAD + quad * 8;
        short8 bh0 = *(const short8*)(Khi + boff);
        short8 bh1 = *(const short8*)(Khi + boff + 32);
        short8 bl0 = *(const short8*)(Klo + boff);
        short8 bl1 = *(const short8*)(Klo + boff + 32);
        f32x4 d0 = {0.f, 0.f, 0.f, 0.f};
        f32x4 d1 = {0.f, 0.f, 0.f, 0.f};
        d0 = __builtin_amdgcn_mfma_f32_16x16x32_bf16(al0, bh0, d0, 0, 0, 0);
        d1 = __builtin_amdgcn_mfma_f32_16x16x32_bf16(al1, bh1, d1, 0, 0, 0);
        d0 = __builtin_amdgcn_mfma_f32_16x16x32_bf16(ah0, bl0, d0, 0, 0, 0);
        d1 = __builtin_amdgcn_mfma_f32_16x16x32_bf16(ah1, bl1, d1, 0, 0, 0);
        d0 = __builtin_amdgcn_mfma_f32_16x16x32_bf16(ah0, bh0, d0, 0, 0, 0);
        d1 = __builtin_amdgcn_mfma_f32_16x16x32_bf16(ah1, bh1, d1, 0, 0, 0);
        // D: row = quad*4+reg (rel), col = n0+mrow
#pragma unroll
        for (int reg = 0; reg < 4; ++reg)
            Sb[(size_t)(quad * 4 + reg) * LSEQ + n0 + mrow] = d0[reg] + d1[reg];
    }
}

// ---------------------------------------------------------------------------
// sparsemax_kernel: one WAVE per (b, q-row). Loops 12 heads: load row from
// Sg, in-register Michelot (warm start, ballot counts, DPP sums), accumulate
// head-mean, write attn row. Zero LDS -> near-full occupancy; TLP hides the
// DPP chain latency that R4-R6 fought with ILP.
// Grid: (CQ/4, B). Block 256 = 4 waves = 4 rows.
// ---------------------------------------------------------------------------
__global__ __launch_bounds__(256) void sparsemax_kernel(
    const float* __restrict__ Sg, float* __restrict__ attn_out,
    int qbase, int CQ) {
    const int t = threadIdx.x;
    const int lane = t & 63;
    const int w = t >> 6;
    const int b = blockIdx.y;
    const int rr = blockIdx.x * 4 + w;         // chunk-relative row

    float accv[16];
#pragma unroll
    for (int j = 0; j < 16; ++j) accv[j] = 0.f;

    for (int h = 0; h < NH; ++h) {
        const float* zrow = Sg + ((size_t)(b * NH + h) * CQ + rr) * LSEQ;
        float z[16];
#pragma unroll
        for (int c = 0; c < 4; ++c)
            *(f32x4*)&z[c * 4] = *(const f32x4*)&zrow[c * 256 + lane * 4];

        // init: tree sum + max, single wave-reduce
        float s0 = 0.f, s1 = 0.f, s2 = 0.f, s3 = 0.f;
        float m0 = z[0], m1 = z[1], m2 = z[2], m3 = z[3];
#pragma unroll
        for (int j = 0; j < 4; ++j) {
            s0 += z[j];      s1 += z[4 + j];
            s2 += z[8 + j];  s3 += z[12 + j];
        }
#pragma unroll
        for (int j = 4; j < 16; j += 4) {
            m0 = fmaxf(m0, z[j]);     m1 = fmaxf(m1, z[j + 1]);
            m2 = fmaxf(m2, z[j + 2]); m3 = fmaxf(m3, z[j + 3]);
        }
        float sv = (s0 + s1) + (s2 + s3);
        float mv = fmaxf(fmaxf(m0, m1), fmaxf(m2, m3));
        wsummaxN<1>(&sv, &mv);

        float tau = fmaxf((sv - 1.0f) * (1.0f / 1024.0f), mv - 1.0f);
        int prev = -1;

        for (int it = 0; it < 32; ++it) {
            float p0 = 0.f, p1 = 0.f, p2 = 0.f, p3 = 0.f;
            int c = 0;
#pragma unroll
            for (int j = 0; j < 4; ++j) {
                bool g0 = z[j]      > tau;
                bool g1 = z[4 + j]  > tau;
                bool g2 = z[8 + j]  > tau;
                bool g3 = z[12 + j] > tau;
                c += __popcll(__ballot(g0)) + __popcll(__ballot(g1))
                   + __popcll(__ballot(g2)) + __popcll(__ballot(g3));
                p0 += g0 ? z[j]      : 0.f;
                p1 += g1 ? z[4 + j]  : 0.f;
                p2 += g2 ? z[8 + j]  : 0.f;
                p3 += g3 ? z[12 + j] : 0.f;
            }
            float s = (p0 + p1) + (p2 + p3);
            wsumN<1>(&s);
            if (c == prev) break;              // support stable -> tau exact
            tau = (s - 1.0f) / (float)c;
            prev = c;
        }

#pragma unroll
        for (int j = 0; j < 16; ++j)
            accv[j] += fmaxf(z[j] - tau, 0.f);
    }

    float* ao = attn_out + ((size_t)b * LSEQ + qbase + rr) * LSEQ;
#pragma unroll
    for (int c = 0; c < 4; ++c) {
        f32x4 o;
#pragma unroll
        for (int j = 0; j < 4; ++j) o[j] = accv[c * 4 + j] * (1.0f / 12.0f);
        *(f32x4*)&ao[c * 256 + lane * 4] = o;
    }
}

// ---------------------------------------------------------------------------
// attn_fused: R4 fallback (only used if ws_size can't hold a score chunk).
// ---------------------------------------------------------------------------
__global__ __launch_bounds__(256, 2) void attn_fused(
    const unsigned short* __restrict__ ws, float* __restrict__ attn_out) {
    __shared__ float S[16 * 1024];

    const unsigned short* Qhi = ws;
    const unsigned short* Qlo = ws + OUT_ELEMS;
    const unsigned short* Khi = ws + 2 * OUT_ELEMS;
    const unsigned short* Klo = ws + 3 * OUT_ELEMS;

    const int t = threadIdx.x;
    const int lane = t & 63;
    const int w = t >> 6;
    const int b = blockIdx.y;
    const int q0 = blockIdx.x * 16;
    const int mrow = lane & 15;
    const int quad = lane >> 4;

    f32x4 acc[4][4];
#pragma unroll
    for (int rr = 0; rr < 4; ++rr)
#pragma unroll
        for (int c = 0; c < 4; ++c) acc[rr][c] = (f32x4){0.f, 0.f, 0.f, 0.f};

    for (int h = 0; h < NH; ++h) {
        const size_t hb = ((size_t)b * NH + h) * (LSEQ * DHEAD);
        const size_t aoff = hb + (size_t)(q0 + mrow) * DHEAD + quad * 8;
        short8 ah0 = *(const short8*)(Qhi + aoff);
        short8 ah1 = *(const short8*)(Qhi + aoff + 32);
        short8 al0 = *(const short8*)(Qlo + aoff);
        short8 al1 = *(const short8*)(Qlo + aoff + 32);

        __syncthreads();
#pragma unroll 4
        for (int nt = 0; nt < 16; ++nt) {
            const int n0 = w * 256 + nt * 16;
            const size_t boff = hb + (size_t)(n0 + mrow) * DHEAD + quad * 8;
            short8 bh0 = *(const short8*)(Khi + boff);
            short8 bh1 = *(const short8*)(Khi + boff + 32);
            short8 bl0 = *(const short8*)(Klo + boff);
            short8 bl1 = *(const short8*)(Klo + boff + 32);
            f32x4 d0 = {0.f, 0.f, 0.f, 0.f};
            f32x4 d1 = {0.f, 0.f, 0.f, 0.f};
            d0 = __builtin_amdgcn_mfma_f32_16x16x32_bf16(al0, bh0, d0, 0, 0, 0);
            d1 = __builtin_amdgcn_mfma_f32_16x16x32_bf16(al1, bh1, d1, 0, 0, 0);
            d0 = __builtin_amdgcn_mfma_f32_16x16x32_bf16(ah0, bl0, d0, 0, 0, 0);
            d1 = __builtin_amdgcn_mfma_f32_16x16x32_bf16(ah1, bl1, d1, 0, 0, 0);
            d0 = __builtin_amdgcn_mfma_f32_16x16x32_bf16(ah0, bh0, d0, 0, 0, 0);
            d1 = __builtin_amdgcn_mfma_f32_16x16x32_bf16(ah1, bh1, d1, 0, 0, 0);
#pragma unroll
            for (int reg = 0; reg < 4; ++reg)
                S[(quad * 4 + reg) * 1024 + n0 + mrow] = d0[reg] + d1[reg];
        }
        __syncthreads();

        float z[4][16];
        float sv[4], mv[4];
#pragma unroll
        for (int rr = 0; rr < 4; ++rr) {
            const int r = w * 4 + rr;
#pragma unroll
            for (int c = 0; c < 4; ++c)
                *(f32x4*)&z[rr][c * 4] = *(const f32x4*)&S[r * 1024 + c * 256 + lane * 4];
            float s0 = 0.f, s1 = 0.f, s2 = 0.f, s3 = 0.f;
            float m0 = z[rr][0], m1 = z[rr][1], m2 = z[rr][2], m3 = z[rr][3];
#pragma unroll
            for (int j = 0; j < 4; ++j) {
                s0 += z[rr][j];      s1 += z[rr][4 + j];
                s2 += z[rr][8 + j];  s3 += z[rr][12 + j];
            }
#pragma unroll
            for (int j = 4; j < 16; j += 4) {
                m0 = fmaxf(m0, z[rr][j]);     m1 = fmaxf(m1, z[rr][j + 1]);
                m2 = fmaxf(m2, z[rr][j + 2]); m3 = fmaxf(m3, z[rr][j + 3]);
            }
            sv[rr] = (s0 + s1) + (s2 + s3);
            mv[rr] = fmaxf(fmaxf(m0, m1), fmaxf(m2, m3));
        }
        wsummaxN<4>(sv, mv);

        float tau[4]; int prev[4]; bool done[4];
#pragma unroll
        for (int rr = 0; rr < 4; ++rr) {
            tau[rr] = fmaxf((sv[rr] - 1.0f) * (1.0f / 1024.0f), mv[rr] - 1.0f);
            prev[rr] = -1; done[rr] = false;
        }
        for (int it = 0; it < 48; ++it) {
            float s4[4]; int c4[4];
#pragma unroll
            for (int rr = 0; rr < 4; ++rr) {
                float s0 = 0.f, s1 = 0.f, s2 = 0.f, s3 = 0.f;
                int c = 0;
#pragma unroll
                for (int j = 0; j < 4; ++j) {
                    bool g0 = z[rr][j]      > tau[rr];
                    bool g1 = z[rr][4 + j]  > tau[rr];
                    bool g2 = z[rr][8 + j]  > tau[rr];
                    bool g3 = z[rr][12 + j] > tau[rr];
                    c += __popcll(__ballot(g0)) + __popcll(__ballot(g1))
                       + __popcll(__ballot(g2)) + __popcll(__ballot(g3));
                    s0 += g0 ? z[rr][j]      : 0.f;
                    s1 += g1 ? z[rr][4 + j]  : 0.f;
                    s2 += g2 ? z[rr][8 + j]  : 0.f;
                    s3 += g3 ? z[rr][12 + j] : 0.f;
                }
                s4[rr] = (s0 + s1) + (s2 + s3); c4[rr] = c;
            }
            wsumN<4>(s4);
            bool alldone = true;
#pragma unroll
            for (int rr = 0; rr < 4; ++rr) {
                if (!done[rr]) {
                    if (c4[rr] == prev[rr]) done[rr] = true;
                    else { tau[rr] = (s4[rr] - 1.0f) / (float)c4[rr]; prev[rr] = c4[rr]; }
                }
                alldone = alldone && done[rr];
            }
            if (alldone) break;
        }
#pragma unroll
        for (int rr = 0; rr < 4; ++rr)
#pragma unroll
            for (int c = 0; c < 4; ++c)
#pragma unroll
                for (int j = 0; j < 4; ++j)
                    acc[rr][c][j] += fmaxf(z[rr][c * 4 + j] - tau[rr], 0.f);
    }

    float* ao = attn_out + ((size_t)b * LSEQ + q0 + w * 4) * LSEQ;
#pragma unroll
    for (int rr = 0; rr < 4; ++rr)
#pragma unroll
        for (int c = 0; c < 4; ++c) {
            f32x4 o = acc[rr][c] * (1.0f / 12.0f);
            *(f32x4*)&ao[(size_t)rr * LSEQ + c * 256 + lane * 4] = o;
        }
}

// ---------------------------------------------------------------------------
// out_mfma: out[b] = attn[b] @ v[b] via split-bf16 3-pass MFMA. UNCHANGED.
// ---------------------------------------------------------------------------
__global__ __launch_bounds__(256) void out_mfma(
    const float* __restrict__ attn, const float* __restrict__ v,
    float* __restrict__ out) {
    const int b = blockIdx.z;
    const float* Ab = attn + (size_t)b * LSEQ * LSEQ;
    const float* Vb = v    + (size_t)b * LSEQ * DMODEL;
    float* Cb       = out  + (size_t)b * LSEQ * DMODEL;

    __shared__ unsigned short Ah[128][32], Al[128][32];
    __shared__ unsigned short Bh[128][36], Bl[128][36];   // pad 36: conflict-free 8B rd/wr

    const int t    = threadIdx.x;
    const int lane = t & 63;
    const int w    = t >> 6;
    const int wr   = w >> 1, wc = w & 1;
    const int mrow = lane & 15, quad = lane >> 4;
    const int m0   = blockIdx.y * 128;
    const int n0   = blockIdx.x * 128;

    const int srow = t >> 3;
    const int scol = (t & 7) * 4;
    const int bn   = t & 127;
    const int bk0  = (t >> 7) * 16;

    f32x4 acc[4][4];
#pragma unroll
    for (int i = 0; i < 4; ++i)
#pragma unroll
        for (int j = 0; j < 4; ++j) acc[i][j] = (f32x4){0.f, 0.f, 0.f, 0.f};

    for (int k0 = 0; k0 < LSEQ; k0 += 32) {
        float4 av[4];
#pragma unroll
        for (int i = 0; i < 4; ++i)
            av[i] = *(const float4*)&Ab[(size_t)(m0 + srow + i * 32) * LSEQ + k0 + scol];
        float bv[16];
#pragma unroll
        for (int i = 0; i < 16; ++i)
            bv[i] = Vb[(size_t)(k0 + bk0 + i) * DMODEL + n0 + bn];

        __syncthreads();
#pragma unroll
        for (int i = 0; i < 4; ++i) {
            ushort4 h4, l4;
            split2(av[i].x, h4.x, l4.x); split2(av[i].y, h4.y, l4.y);
            split2(av[i].z, h4.z, l4.z); split2(av[i].w, h4.w, l4.w);
            *(ushort4*)&Ah[srow + i * 32][scol] = h4;
            *(ushort4*)&Al[srow + i * 32][scol] = l4;
        }
#pragma unroll
        for (int g = 0; g < 4; ++g) {
            ushort4 h4, l4;
            split2(bv[g * 4 + 0], h4.x, l4.x); split2(bv[g * 4 + 1], h4.y, l4.y);
            split2(bv[g * 4 + 2], h4.z, l4.z); split2(bv[g * 4 + 3], h4.w, l4.w);
            *(ushort4*)&Bh[bn][bk0 + g * 4] = h4;
            *(ushort4*)&Bl[bn][bk0 + g * 4] = l4;
        }
        __syncthreads();

        short8 ah[4], al[4], bh[4], bl[4];
#pragma unroll
        for (int i = 0; i < 4; ++i) {
            ah[i] = *(const short8*)&Ah[wr * 64 + i * 16 + mrow][quad * 8];
            al[i] = *(const short8*)&Al[wr * 64 + i * 16 + mrow][quad * 8];
        }
#pragma unroll
        for (int j = 0; j < 4; ++j) {
            const unsigned short* ph = &Bh[wc * 64 + j * 16 + mrow][quad * 8];
            const unsigned short* pl = &Bl[wc * 64 + j * 16 + mrow][quad * 8];
            uint2 h0 = *(const uint2*)ph;
            uint2 h1 = *(const uint2*)(ph + 4);
            uint2 l0 = *(const uint2*)pl;
            uint2 l1 = *(const uint2*)(pl + 4);
            union { uint u[4]; short8 s; } ch, cl;
            ch.u[0] = h0.x; ch.u[1] = h0.y; ch.u[2] = h1.x; ch.u[3] = h1.y;
            cl.u[0] = l0.x; cl.u[1] = l0.y; cl.u[2] = l1.x; cl.u[3] = l1.y;
            bh[j] = ch.s; bl[j] = cl.s;
        }
#pragma unroll
        for (int i = 0; i < 4; ++i)
#pragma unroll
            for (int j = 0; j < 4; ++j) {
                acc[i][j] = __builtin_amdgcn_mfma_f32_16x16x32_bf16(al[i], bh[j], acc[i][j], 0, 0, 0);
                acc[i][j] = __builtin_amdgcn_mfma_f32_16x16x32_bf16(ah[i], bl[j], acc[i][j], 0, 0, 0);
                acc[i][j] = __builtin_amdgcn_mfma_f32_16x16x32_bf16(ah[i], bh[j], acc[i][j], 0, 0, 0);
            }
    }

#pragma unroll
    for (int i = 0; i < 4; ++i)
#pragma unroll
        for (int j = 0; j < 4; ++j)
#pragma unroll
            for (int reg = 0; reg < 4; ++reg) {
                const int mg = m0 + wr * 64 + i * 16 + quad * 4 + reg;
                const int ng = n0 + wc * 64 + j * 16 + mrow;
                Cb[(size_t)mg * DMODEL + ng] = acc[i][j][reg];
            }
}

extern "C" void kernel_launch(void* const* d_in, const int* in_sizes, int n_in,
                              void* d_out, int out_size, void* d_ws, size_t ws_size,
                              hipStream_t stream) {
    const float* q  = (const float*)d_in[0];
    const float* k  = (const float*)d_in[1];
    const float* v  = (const float*)d_in[2];
    const float* Wq = (const float*)d_in[3];
    const float* bq = (const float*)d_in[4];
    const float* Wk = (const float*)d_in[5];
    const float* bk = (const float*)d_in[6];

    float* out  = (float*)d_out;                 // [8,1024,768]
    float* attn = out + OUT_ELEMS;               // [8,1024,1024]
    unsigned short* ws = (unsigned short*)d_ws;  // Qhi|Qlo|Khi|Klo bf16 planes

    const size_t plane_bytes = (size_t)4 * OUT_ELEMS * sizeof(unsigned short); // 50331648

    // 1) projections
    hipLaunchKernelGGL(proj_mfma, dim3(6, 64, 2), dim3(256), 0, stream,
                       q, k, Wq, bq, Wk, bk, ws);

    // pick largest q-chunk whose score buffer fits after the bf16 planes
    int CQ = 0;
    for (int cand = 1024; cand >= 64; cand >>= 1) {
        size_t need = (size_t)BSZ * NH * cand * LSEQ * sizeof(float);
        if (plane_bytes + need <= ws_size) { CQ = cand; break; }
    }

    if (CQ > 0) {
        float* Sg = (float*)((char*)d_ws + plane_bytes);
        for (int qbase = 0; qbase < LSEQ; qbase += CQ) {
            hipLaunchKernelGGL(score_kernel, dim3(CQ / 16, BSZ * NH), dim3(256), 0, stream,
                               ws, Sg, qbase, CQ);
            hipLaunchKernelGGL(sparsemax_kernel, dim3(CQ / 4, BSZ), dim3(256), 0, stream,
                               Sg, attn, qbase, CQ);
        }
    } else {
        hipLaunchKernelGGL(attn_fused, dim3(64, 8), dim3(256), 0, stream, ws, attn);
    }

    // 3) output = attn @ v
    hipLaunchKernelGGL(out_mfma, dim3(6, 8, 8), dim3(256), 0, stream,
                       attn, v, out);
}